// Round 2
// baseline (1132.685 us; speedup 1.0000x reference)
//
#include <hip/hip_runtime.h>
#include <math.h>

// Problem constants (fixed by reference)
#define BATCH 2048
#define CH    32      // C
#define NN    144     // H*W
#define KNN   9

// exact GELU: x * 0.5 * (1 + erf(x/sqrt(2)))  (jax.nn.gelu approximate=False)
__device__ __forceinline__ float gelu_exact(float x) {
    return 0.5f * x * (1.0f + erff(x * 0.70710678118654752440f));
}

// One workgroup per batch element. 256 threads.
__global__ __launch_bounds__(256) void gcn_main(
        const float* __restrict__ xin,   // (B, C, H, W)
        const float* __restrict__ pos,   // (1, C, H, W)
        const float* __restrict__ rel,   // (1, N, N)
        const float* __restrict__ W1,  const float* __restrict__ B1,   // g_fc1 (32x32)
        const float* __restrict__ WC,  const float* __restrict__ BC,   // g_conv (64x64)
        const float* __restrict__ W2,  const float* __restrict__ B2,   // g_fc2 (32x64)
        const float* __restrict__ F1,  const float* __restrict__ FB1,  // f_fc1 (32x32)
        const float* __restrict__ F2,  const float* __restrict__ FB2,  // f_fc2 (32x32)
        float* __restrict__ out) {
    const int b = blockIdx.x;
    const int t = threadIdx.x;

    __shared__ __align__(16) float s_tmp[CH * NN];   // x = input + pos  (c*NN + n)
    __shared__ __align__(16) float s_xf[CH * NN];    // g_fc1 output
    __shared__ float s_sq[NN];
    __shared__ float s_rinv[NN];
    __shared__ __align__(16) float s_w[6144];        // staged weights (reused)
    __shared__ float s_b[192];                       // all biases

    const float* xb = xin + (size_t)b * (CH * NN);

    // ---- stage biases + g_fc1 weights; phase 1: x = input + pos ----
    for (int i = t; i < 32; i += 256)  s_b[i] = B1[i];
    for (int i = t; i < 64; i += 256)  s_b[32 + i] = BC[i];
    if (t < 32) { s_b[96 + t] = B2[t]; s_b[128 + t] = FB1[t]; s_b[160 + t] = FB2[t]; }
    for (int i = t; i < 1024; i += 256) s_w[i] = W1[i];
    {
        const float4* x4 = (const float4*)xb;
        const float4* p4 = (const float4*)pos;
        float4* t4 = (float4*)s_tmp;
        for (int i = t; i < (CH * NN) / 4; i += 256) {
            float4 a = x4[i], p = p4[i];
            t4[i] = make_float4(a.x + p.x, a.y + p.y, a.z + p.z, a.w + p.w);
        }
    }
    __syncthreads();

    // ---- phase 2: xf = g_fc1_w @ x + g_fc1_b ----
    for (int i = t; i < CH * NN; i += 256) {
        int o = i / NN, n = i - o * NN;
        float acc = s_b[o];
        #pragma unroll
        for (int c = 0; c < CH; ++c) acc += s_w[o * CH + c] * s_tmp[c * NN + n];
        s_xf[i] = acc;
    }
    __syncthreads();

    // ---- phase 3: column norms; stage g_conv + g_fc2 weights ----
    if (t < NN) {
        float sum = 0.f;
        #pragma unroll
        for (int c = 0; c < CH; ++c) { float v = s_xf[c * NN + t]; sum += v * v; }
        float r = 1.0f / fmaxf(sqrtf(sum), 1e-12f);
        s_rinv[t] = r;
        s_sq[t]   = sum * r * r;   // == ||xn||^2 (≈1)
    }
    for (int i = t; i < 4096; i += 256) s_w[i]        = WC[i];
    for (int i = t; i < 2048; i += 256) s_w[4096 + i] = W2[i];
    __syncthreads();

    // ---- phase 4 + fused Grapher tail (per column n = t) ----
    float x2r[CH];   // lives across the weight-swap barrier
    int   besti[KNN];
    if (t < NN) {
        const int n = t;
        const float r   = s_rinv[n];
        const float sqn = s_sq[n];
        float xnc[CH];
        #pragma unroll
        for (int c = 0; c < CH; ++c) xnc[c] = s_xf[c * NN + n] * r;

        float bestd[KNN];
        #pragma unroll
        for (int k = 0; k < KNN; ++k) { bestd[k] = INFINITY; besti[k] = 0; }

        const float* reln = rel + n * NN;
        for (int m = 0; m < NN; ++m) {
            float dot = 0.f;
            #pragma unroll
            for (int c = 0; c < CH; ++c) dot += xnc[c] * s_xf[c * NN + m];
            float d = sqn - 2.0f * (dot * s_rinv[m]) + s_sq[m] + reln[m];
            // insertion keeping sorted ascending; strict < matches lax.top_k
            // tie-break (lower index wins, since m ascends)
            if (d < bestd[KNN - 1]) {
                bestd[KNN - 1] = d; besti[KNN - 1] = m;
                #pragma unroll
                for (int k = KNN - 1; k > 0; --k) {
                    if (bestd[k] < bestd[k - 1]) {
                        float td = bestd[k]; bestd[k] = bestd[k - 1]; bestd[k - 1] = td;
                        int   ti = besti[k]; besti[k] = besti[k - 1]; besti[k - 1] = ti;
                    }
                }
            }
        }

        // max-relative aggregation -> interleaved stacked column st[2c]=xf, st[2c+1]=maxrel
        float stc[2 * CH];
        #pragma unroll
        for (int c = 0; c < CH; ++c) {
            float xfv = s_xf[c * NN + n];
            float mx = -INFINITY;
            #pragma unroll
            for (int k = 0; k < KNN; ++k) mx = fmaxf(mx, s_xf[c * NN + besti[k]]);
            stc[2 * c]     = xfv;
            stc[2 * c + 1] = mx - xfv;
        }

        // hc = gelu(g_conv_w @ st + b)
        float hcv[2 * CH];
        #pragma unroll
        for (int j = 0; j < 2 * CH; ++j) {
            float acc = s_b[32 + j];
            const float4* w4 = (const float4*)&s_w[j * 2 * CH];
            #pragma unroll
            for (int q = 0; q < 16; ++q) {
                float4 w = w4[q];
                acc += w.x * stc[4 * q] + w.y * stc[4 * q + 1]
                     + w.z * stc[4 * q + 2] + w.w * stc[4 * q + 3];
            }
            hcv[j] = gelu_exact(acc);
        }

        // x2 = g_fc2_w @ hc + b + tmp (residual)
        #pragma unroll
        for (int o = 0; o < CH; ++o) {
            float acc = s_b[96 + o] + s_tmp[o * NN + n];
            const float4* w4 = (const float4*)&s_w[4096 + o * 64];
            #pragma unroll
            for (int q = 0; q < 16; ++q) {
                float4 w = w4[q];
                acc += w.x * hcv[4 * q] + w.y * hcv[4 * q + 1]
                     + w.z * hcv[4 * q + 2] + w.w * hcv[4 * q + 3];
            }
            x2r[o] = acc;
        }
    }
    __syncthreads();

    // ---- swap in FFN weights ----
    for (int i = t; i < 1024; i += 256) s_w[i]        = F1[i];
    for (int i = t; i < 1024; i += 256) s_w[1024 + i] = F2[i];
    __syncthreads();

    // ---- FFN + residual + store ----
    if (t < NN) {
        const int n = t;
        float yv[CH];
        #pragma unroll
        for (int o = 0; o < CH; ++o) {
            float acc = s_b[128 + o];
            const float4* w4 = (const float4*)&s_w[o * CH];
            #pragma unroll
            for (int q = 0; q < 8; ++q) {
                float4 w = w4[q];
                acc += w.x * x2r[4 * q] + w.y * x2r[4 * q + 1]
                     + w.z * x2r[4 * q + 2] + w.w * x2r[4 * q + 3];
            }
            yv[o] = gelu_exact(acc);
        }
        float* ob = out + (size_t)b * (CH * NN);
        #pragma unroll
        for (int o = 0; o < CH; ++o) {
            float acc = s_b[160 + o];
            const float4* w4 = (const float4*)&s_w[1024 + o * CH];
            #pragma unroll
            for (int q = 0; q < 8; ++q) {
                float4 w = w4[q];
                acc += w.x * yv[4 * q] + w.y * yv[4 * q + 1]
                     + w.z * yv[4 * q + 2] + w.w * yv[4 * q + 3];
            }
            ob[o * NN + n] = acc + x2r[o];
        }
    }
}

extern "C" void kernel_launch(void* const* d_in, const int* in_sizes, int n_in,
                              void* d_out, int out_size, void* d_ws, size_t ws_size,
                              hipStream_t stream) {
    const float* xin = (const float*)d_in[0];
    const float* pos = (const float*)d_in[1];
    const float* rel = (const float*)d_in[2];
    const float* w1  = (const float*)d_in[3];
    const float* b1  = (const float*)d_in[4];
    const float* wc  = (const float*)d_in[5];
    const float* bc  = (const float*)d_in[6];
    const float* w2  = (const float*)d_in[7];
    const float* b2  = (const float*)d_in[8];
    const float* f1  = (const float*)d_in[9];
    const float* fb1 = (const float*)d_in[10];
    const float* f2  = (const float*)d_in[11];
    const float* fb2 = (const float*)d_in[12];
    float* out = (float*)d_out;

    dim3 grid(BATCH), blk(256);
    gcn_main<<<grid, blk, 0, stream>>>(xin, pos, rel,
                                       w1, b1, wc, bc, w2, b2,
                                       f1, fb1, f2, fb2, out);
}

// Round 3
// 564.989 us; speedup vs baseline: 2.0048x; 2.0048x over previous
//
#include <hip/hip_runtime.h>
#include <math.h>

// Problem constants (fixed by reference)
#define BATCH 2048
#define CH    32      // C
#define NN    144     // H*W = 12*12
#define KNN   9
#define PAD   36      // LDS row stride (floats): 16B-aligned, even bank spread

// exact GELU: x * 0.5 * (1 + erf(x/sqrt(2)))  (jax.nn.gelu approximate=False)
__device__ __forceinline__ float gelu_exact(float x) {
    return 0.5f * x * (1.0f + erff(x * 0.70710678118654752440f));
}

// One workgroup per batch element. 256 threads, 3 blocks/CU (LDS 47.2KB).
__global__ __launch_bounds__(256, 3) void gcn_main(
        const float* __restrict__ xin,   // (B, C, H, W)
        const float* __restrict__ pos,   // (1, C, H, W)
        const float* __restrict__ rel,   // (1, N, N)
        const float* __restrict__ W1,  const float* __restrict__ B1,   // g_fc1 32x32
        const float* __restrict__ WC,  const float* __restrict__ BC,   // g_conv 64x64
        const float* __restrict__ W2,  const float* __restrict__ B2,   // g_fc2 32x64
        const float* __restrict__ F1,  const float* __restrict__ FB1,  // f_fc1 32x32
        const float* __restrict__ F2,  const float* __restrict__ FB2,  // f_fc2 32x32
        float* __restrict__ out) {
    const int b = blockIdx.x;
    const int t = threadIdx.x;

    __shared__ __align__(16) float s_tmpT[NN * PAD];  // (n,c): x = input+pos
    __shared__ __align__(16) float s_xfT[NN * PAD];   // (n,c): g_fc1 output
    __shared__ __align__(16) float s_W1p[CH * PAD];   // W1 rows, padded
    __shared__ float s_sq[NN];
    __shared__ float s_rinv[NN];

    // ---- phase 1: tmp = x + pos, transposed (c,n)->(n,c) into LDS ----
    {
        const float4* x4 = (const float4*)(xin + (size_t)b * (CH * NN));
        const float4* p4 = (const float4*)pos;
        for (int i = t; i < (CH * NN) / 4; i += 256) {
            float4 a = x4[i], p = p4[i];
            int idx = 4 * i;
            int c = idx / NN, n = idx - c * NN;    // n%4==0, no row crossing
            float* dst = &s_tmpT[n * PAD + c];
            dst[0]       = a.x + p.x;
            dst[PAD]     = a.y + p.y;
            dst[2 * PAD] = a.z + p.z;
            dst[3 * PAD] = a.w + p.w;
        }
        // stage W1 (32x32) into padded LDS rows
        if (t < 256) {
            int c = t >> 3, q = t & 7;
            ((float4*)&s_W1p[c * PAD])[q] = ((const float4*)W1)[t];
        }
    }
    __syncthreads();

    // ---- phase 2: xfT[n][c] = B1[c] + sum_c' W1[c][c'] * tmpT[n][c'] ----
    {
        const int c = t & 31, n0 = t >> 5;   // n0 in [0,8)
        float w[CH];
        const float4* wr = (const float4*)&s_W1p[c * PAD];
        #pragma unroll
        for (int q = 0; q < 8; ++q) {
            float4 v = wr[q];
            w[4*q] = v.x; w[4*q+1] = v.y; w[4*q+2] = v.z; w[4*q+3] = v.w;
        }
        const float bias = B1[c];
        #pragma unroll
        for (int r = 0; r < 18; ++r) {
            int n = n0 + 8 * r;
            const float4* row = (const float4*)&s_tmpT[n * PAD];
            float acc = bias;
            #pragma unroll
            for (int q = 0; q < 8; ++q) {
                float4 v = row[q];
                acc += w[4*q] * v.x + w[4*q+1] * v.y + w[4*q+2] * v.z + w[4*q+3] * v.w;
            }
            s_xfT[n * PAD + c] = acc;
        }
    }
    __syncthreads();

    // ---- phase 3: column norms ----
    if (t < NN) {
        const float4* row = (const float4*)&s_xfT[t * PAD];
        float sum = 0.f;
        #pragma unroll
        for (int q = 0; q < 8; ++q) {
            float4 v = row[q];
            sum += v.x * v.x + v.y * v.y + v.z * v.z + v.w * v.w;
        }
        float r = 1.0f / fmaxf(sqrtf(sum), 1e-12f);
        s_rinv[t] = r;
        s_sq[t]   = sum * r * r;
    }
    __syncthreads();

    if (t >= NN) return;   // no further barriers; tail is per-thread
    const int n = t;

    // ---- phase 4: k-NN over distance rows ----
    float xnc[CH];
    {
        const float rr = s_rinv[n];
        const float4* row = (const float4*)&s_xfT[n * PAD];
        #pragma unroll
        for (int q = 0; q < 8; ++q) {
            float4 v = row[q];
            xnc[4*q] = v.x * rr; xnc[4*q+1] = v.y * rr;
            xnc[4*q+2] = v.z * rr; xnc[4*q+3] = v.w * rr;
        }
    }
    const float sqn = s_sq[n];
    float bestd[KNN];
    int   besti[KNN];
    #pragma unroll
    for (int k = 0; k < KNN; ++k) { bestd[k] = INFINITY; besti[k] = 0; }

    const float* reln = rel + n * NN;
    for (int mb = 0; mb < NN / 16; ++mb) {
        float rl[16];
        const float4* rp = (const float4*)(reln + mb * 16);
        #pragma unroll
        for (int q = 0; q < 4; ++q) {
            float4 v = rp[q];
            rl[4*q] = v.x; rl[4*q+1] = v.y; rl[4*q+2] = v.z; rl[4*q+3] = v.w;
        }
        #pragma unroll
        for (int mm = 0; mm < 16; ++mm) {
            const int m = mb * 16 + mm;
            const float4* row = (const float4*)&s_xfT[m * PAD];
            float dot = 0.f;
            #pragma unroll
            for (int q = 0; q < 8; ++q) {
                float4 v = row[q];
                dot += xnc[4*q] * v.x + xnc[4*q+1] * v.y
                     + xnc[4*q+2] * v.z + xnc[4*q+3] * v.w;
            }
            float d = sqn - 2.0f * (dot * s_rinv[m]) + s_sq[m] + rl[mm];
            // strict < matches lax.top_k tie-break (lower index wins; m ascends)
            if (d < bestd[KNN - 1]) {
                bestd[KNN - 1] = d; besti[KNN - 1] = m;
                #pragma unroll
                for (int k = KNN - 1; k > 0; --k) {
                    if (bestd[k] < bestd[k - 1]) {
                        float td = bestd[k]; bestd[k] = bestd[k - 1]; bestd[k - 1] = td;
                        int   ti = besti[k]; besti[k] = besti[k - 1]; besti[k - 1] = ti;
                    }
                }
            }
        }
    }

    // ---- phase 5: max-relative -> interleaved stacked column ----
    float stc[2 * CH];   // stc[2c]=xf, stc[2c+1]=max_k xf[nbr]-xf
    {
        const float4* row = (const float4*)&s_xfT[n * PAD];
        #pragma unroll
        for (int q = 0; q < 8; ++q) {
            float4 v = row[q];
            stc[8*q + 0] = v.x; stc[8*q + 2] = v.y;
            stc[8*q + 4] = v.z; stc[8*q + 6] = v.w;
        }
        #pragma unroll
        for (int c = 0; c < CH; ++c) stc[2*c + 1] = -INFINITY;
        #pragma unroll
        for (int k = 0; k < KNN; ++k) {
            const float4* nr = (const float4*)&s_xfT[besti[k] * PAD];
            #pragma unroll
            for (int q = 0; q < 8; ++q) {
                float4 v = nr[q];
                stc[8*q + 1] = fmaxf(stc[8*q + 1], v.x);
                stc[8*q + 3] = fmaxf(stc[8*q + 3], v.y);
                stc[8*q + 5] = fmaxf(stc[8*q + 5], v.z);
                stc[8*q + 7] = fmaxf(stc[8*q + 7], v.w);
            }
        }
        #pragma unroll
        for (int c = 0; c < CH; ++c) stc[2*c + 1] -= stc[2*c];
    }

    // ---- phase 6: hc = gelu(WC@stc+BC); x2r = W2@hc + B2 + tmp (streamed) ----
    float x2r[CH];
    {
        const float4* trow = (const float4*)&s_tmpT[n * PAD];
        #pragma unroll
        for (int q = 0; q < 8; ++q) {
            float4 v = trow[q];
            x2r[4*q]   = B2[4*q]   + v.x;
            x2r[4*q+1] = B2[4*q+1] + v.y;
            x2r[4*q+2] = B2[4*q+2] + v.z;
            x2r[4*q+3] = B2[4*q+3] + v.w;
        }
    }
    #pragma unroll 4
    for (int j = 0; j < 2 * CH; ++j) {
        float acc = BC[j];
        #pragma unroll
        for (int c = 0; c < 2 * CH; ++c) acc += WC[j * 2 * CH + c] * stc[c];
        float h = gelu_exact(acc);
        #pragma unroll
        for (int o = 0; o < CH; ++o) x2r[o] += W2[o * 2 * CH + j] * h;
    }

    // ---- phase 7: FFN + residual + store ----
    float yv[CH];
    #pragma unroll
    for (int o = 0; o < CH; ++o) {
        float acc = FB1[o];
        #pragma unroll
        for (int c = 0; c < CH; ++c) acc += F1[o * CH + c] * x2r[c];
        yv[o] = gelu_exact(acc);
    }
    float* ob = out + (size_t)b * (CH * NN) + n;
    #pragma unroll
    for (int o = 0; o < CH; ++o) {
        float acc = FB2[o];
        #pragma unroll
        for (int c = 0; c < CH; ++c) acc += F2[o * CH + c] * yv[c];
        ob[o * NN] = acc + x2r[o];
    }
}

extern "C" void kernel_launch(void* const* d_in, const int* in_sizes, int n_in,
                              void* d_out, int out_size, void* d_ws, size_t ws_size,
                              hipStream_t stream) {
    const float* xin = (const float*)d_in[0];
    const float* pos = (const float*)d_in[1];
    const float* rel = (const float*)d_in[2];
    const float* w1  = (const float*)d_in[3];
    const float* b1  = (const float*)d_in[4];
    const float* wc  = (const float*)d_in[5];
    const float* bc  = (const float*)d_in[6];
    const float* w2  = (const float*)d_in[7];
    const float* b2  = (const float*)d_in[8];
    const float* f1  = (const float*)d_in[9];
    const float* fb1 = (const float*)d_in[10];
    const float* f2  = (const float*)d_in[11];
    const float* fb2 = (const float*)d_in[12];
    float* out = (float*)d_out;

    dim3 grid(BATCH), blk(256);
    gcn_main<<<grid, blk, 0, stream>>>(xin, pos, rel,
                                       w1, b1, wc, bc, w2, b2,
                                       f1, fb1, f2, fb2, out);
}